// Round 8
// baseline (104.378 us; speedup 1.0000x reference)
//
#include <hip/hip_runtime.h>
#include <math.h>
#include <stdint.h>

#define NP 288               // 274 padded to 18*16
#define OUT_H (2*512*64)

typedef _Float16 f16;
typedef __attribute__((ext_vector_type(2))) _Float16 f16x2;
typedef __attribute__((ext_vector_type(4))) _Float16 f16x4;
typedef __attribute__((ext_vector_type(8))) _Float16 f16x8;
typedef __attribute__((ext_vector_type(4))) float f32x4;

static __device__ __forceinline__ f16x2 pkrtz(float a, float b) {
    return __builtin_bit_cast(f16x2, __builtin_amdgcn_cvt_pkrtz(a, b));
}

#if defined(__has_builtin)
#if __has_builtin(__builtin_amdgcn_mfma_f32_16x16x16f16)
#define HAVE_MFMA16 1
#endif
#endif

static __device__ __forceinline__ f32x4 mfma16(f16x4 a, f16x4 b, f32x4 c) {
#ifdef HAVE_MFMA16
    return __builtin_amdgcn_mfma_f32_16x16x16f16(a, b, c, 0, 0, 0);
#else
    f32x4 d;
    asm volatile("v_mfma_f32_16x16x16_f16 %0, %1, %2, %3\n\ts_nop 7\n\ts_nop 7"
                 : "=v"(d) : "v"(a), "v"(b), "v"(c));
    return d;
#endif
}

// relu + pack f32x4 -> f16x4 (pkrtz is monotone and exact at 0, so
// max-after-pack == pack-after-max; uses v_pk_max_f16)
static __device__ __forceinline__ f16x4 relupack(f32x4 h) {
    f16x2 lo = pkrtz(h[0], h[1]);
    f16x2 hi = pkrtz(h[2], h[3]);
    const f16x2 z = {(_Float16)0, (_Float16)0};
    lo = __builtin_elementwise_max(lo, z);
    hi = __builtin_elementwise_max(hi, z);
    return __builtin_shufflevector(lo, hi, 0, 1, 2, 3);
}

// ---------------------------------------------------------------------------
// Kernel A: precompute (e-padded to 288 with zeros)
//   Q1[n][288]  f16 = b1e + feats[n] @ w1e[0:64]   (i-side, includes bias)
//   P2[n][288]  f32 = feats[n] @ w1e[64:128]       (j-side, f32 -> MFMA C direct)
//   Wd[9][288]  f16 = w1e[128+k]                   (dist-enc rows)
//   W2F[18][64]x4 f16: per-lane B2 frags W2F[S][c+16g][jj] = w2e[S*16+g*4+jj][c]
//   W1CB[4][16][32] f16 = w1c[k][16T+c] (k<16 else 0)  (coor-MLP A-frag)
// ---------------------------------------------------------------------------
__global__ __launch_bounds__(256) void egnn_pre(
    const float* __restrict__ feats, const float* __restrict__ w1e,
    const float* __restrict__ b1e,   const float* __restrict__ w2e,
    const float* __restrict__ w1c,
    f16* __restrict__ Q1, float* __restrict__ P2, f16* __restrict__ Wd,
    f16* __restrict__ W2F, f16* __restrict__ W1CB)
{
    int id = blockIdx.x * 256 + threadIdx.x;
    const int NN = 1024 * NP;
    if (id < 2 * NN) {
        int hf = id / NN, r = id % NN;
        int n = r / NP, e = r % NP;
        float a = 0.f;
        if (e < 274) {
            a = hf ? 0.f : b1e[e];
            const float* fp = feats + n * 64;
            const float* wp = w1e + hf * 64 * 274 + e;
            #pragma unroll 8
            for (int d2 = 0; d2 < 64; ++d2) a += fp[d2] * wp[d2 * 274];
        }
        if (hf) P2[n * NP + e] = a;
        else    Q1[n * NP + e] = (f16)a;
    } else {
        int x = id - 2 * NN;
        if (x < 9 * NP) {
            int e = x % NP, k = x / NP;
            Wd[x] = (f16)(e < 274 ? w1e[(128 + k) * 274 + e] : 0.f);
        } else if (x < 9 * NP + 1152) {
            int y = x - 9 * NP;                  // 0..1151
            int S = y >> 6, l = y & 63, cc = l & 15, gg = l >> 4;
            f16x4 v = {0, 0, 0, 0};
            #pragma unroll
            for (int jj = 0; jj < 4; ++jj) {
                int e = S * 16 + gg * 4 + jj;
                v[jj] = (f16)(e < 274 ? w2e[e * 16 + cc] : 0.f);
            }
            *(f16x4*)(W2F + y * 4) = v;
        } else if (x < 9 * NP + 1152 + 2048) {
            int y = x - 9 * NP - 1152;           // 0..2047
            int T = y >> 9, rem = y & 511, c2 = rem >> 5, k = rem & 31;
            W1CB[y] = (f16)(k < 16 ? w1c[k * 64 + T * 16 + c2] : 0.f);
        }
    }
}

// ---------------------------------------------------------------------------
// Kernel B: one block per (b,i). 4 waves x 128 j each.
// Phase 1: 2-unit ILP, S in pairs, static double-buffered f32 C prefetch.
//   Per (unit,S): D1 = WdAug(A) x encAug(B) + P2(C,f32) [= pre^T tile],
//   relu+pk-pack -> A-frag of  m += H(A) x w2e^T(B).
// Phase 2: coor MLP via MFMA, reductions, node MLP.
// ---------------------------------------------------------------------------
__global__ __launch_bounds__(256) void egnn_edge(
    const float* __restrict__ feats, const float* __restrict__ coors,
    const float* __restrict__ b2e,   const float* __restrict__ b1c,
    const float* __restrict__ w2c,   const float* __restrict__ b2cv,
    const float* __restrict__ w1h,   const float* __restrict__ b1h,
    const float* __restrict__ w2h,   const float* __restrict__ b2h,
    const f16* __restrict__ Q1,  const float* __restrict__ P2,
    const f16* __restrict__ Wd,  const f16* __restrict__ W2F,
    const f16* __restrict__ W1CB, float* __restrict__ out)
{
    __shared__ f16x8 sAB[1152];         // 18432 B: {A1,B2} frags per (S,lane)
    __shared__ __align__(16) f16 sM[512 * 16];   // 16384 B: m_ij
    __shared__ float sHid[128];
    __shared__ float sRedM[4][16];
    __shared__ float sRedC[4][3];
    __shared__ float sFin[16];

    const int bi = blockIdx.x, bb = bi >> 9;
    const int t = threadIdx.x;
    const int lane = t & 63, wv = t >> 6;
    const int c = lane & 15, g = lane >> 4;

    // ---- block init: fused {A1|B2} fragment array (fold Q1 into k=9) ----
    {
        const f16* Q1r = Q1 + bi * NP;
        for (int x = t; x < 1152; x += 256) {
            int S = x >> 6, l = x & 63, cc = l & 15, gg = l >> 4;
            int e = S * 16 + cc;
            f16x8 v = {0, 0, 0, 0, 0, 0, 0, 0};
            if (gg == 0)      { v[0]=Wd[0*NP+e]; v[1]=Wd[1*NP+e]; v[2]=Wd[2*NP+e]; v[3]=Wd[3*NP+e]; }
            else if (gg == 1) { v[0]=Wd[4*NP+e]; v[1]=Wd[5*NP+e]; v[2]=Wd[6*NP+e]; v[3]=Wd[7*NP+e]; }
            else if (gg == 2) { v[0]=Wd[8*NP+e]; v[1]=Q1r[e]; }
            const f16x4 w = *(const f16x4*)(W2F + x * 4);
            v[4] = w[0]; v[5] = w[1]; v[6] = w[2]; v[7] = w[3];
            sAB[x] = v;
        }
    }
    const float b2e_c = b2e[c];
    const float cix = coors[bi * 3 + 0];
    const float ciy = coors[bi * 3 + 1];
    const float ciz = coors[bi * 3 + 2];
    __syncthreads();

    const float* P2b = P2 + (bb << 9) * NP;

    // ================= Phase 1: edge MLP, 2-unit ILP + static dbuf ==========
    #pragma unroll 1
    for (int pass = 0; pass < 2; ++pass) {
        const int jbase = wv * 128 + pass * 64;
        #pragma unroll 1
        for (int pr = 0; pr < 2; ++pr) {
            f16x4 b1u[2];
            const float* cpp[2];
            #pragma unroll
            for (int u = 0; u < 2; ++u) {
                const int j = jbase + (pr * 2 + u) * 16 + c;
                const int jg = (bb << 9) + j;
                float rx = cix - coors[jg * 3 + 0];
                float ry = ciy - coors[jg * 3 + 1];
                float rz = ciz - coors[jg * 3 + 2];
                float sq = rx * rx + ry * ry + rz * rz;
                float d = sq > 0.f ? sqrtf(sq) : 0.f;
                float en[8];
                #pragma unroll
                for (int k = 0; k < 4; ++k)
                    __sincosf(d * (1.f / (float)(1 << k)), &en[k], &en[4 + k]);
                f16x2 p01 = pkrtz(en[0], en[1]);
                f16x2 p23 = pkrtz(en[2], en[3]);
                f16x2 p45 = pkrtz(en[4], en[5]);
                f16x2 p67 = pkrtz(en[6], en[7]);
                f16x2 pd1 = pkrtz(d, 1.0f);
                f16x2 zz = {(_Float16)0, (_Float16)0};
                f16x2 lo = (g == 0) ? p01 : (g == 1) ? p45 : (g == 2) ? pd1 : zz;
                f16x2 hi = (g == 0) ? p23 : (g == 1) ? p67 : zz;
                b1u[u] = __builtin_shufflevector(lo, hi, 0, 1, 2, 3);
                cpp[u] = P2b + j * NP + g * 4;
            }

            f32x4 acc0 = {0,0,0,0}, acc1 = {0,0,0,0};
            // prologue: f32 C-frags for S=0,1 (both units)
            f32x4 cA0 = *(const f32x4*)(cpp[0]);
            f32x4 cB0 = *(const f32x4*)(cpp[1]);
            f32x4 cA1 = *(const f32x4*)(cpp[0] + 16);
            f32x4 cB1 = *(const f32x4*)(cpp[1] + 16);

            #pragma unroll
            for (int S2 = 0; S2 < 9; ++S2) {
                const int S = 2 * S2;
                f32x4 nA0, nB0, nA1, nB1;
                if (S2 < 8) {
                    nA0 = *(const f32x4*)(cpp[0] + (S + 2) * 16);
                    nB0 = *(const f32x4*)(cpp[1] + (S + 2) * 16);
                    nA1 = *(const f32x4*)(cpp[0] + (S + 3) * 16);
                    nB1 = *(const f32x4*)(cpp[1] + (S + 3) * 16);
                }
                // ---- step S ----
                {
                    f16x8 ab = sAB[S * 64 + lane];
                    f16x4 a1 = __builtin_shufflevector(ab, ab, 0, 1, 2, 3);
                    f16x4 b2 = __builtin_shufflevector(ab, ab, 4, 5, 6, 7);
                    f32x4 h0 = mfma16(a1, b1u[0], cA0);
                    f32x4 h1 = mfma16(a1, b1u[1], cB0);
                    acc0 = mfma16(relupack(h0), b2, acc0);
                    acc1 = mfma16(relupack(h1), b2, acc1);
                }
                // ---- step S+1 ----
                {
                    f16x8 ab = sAB[(S + 1) * 64 + lane];
                    f16x4 a1 = __builtin_shufflevector(ab, ab, 0, 1, 2, 3);
                    f16x4 b2 = __builtin_shufflevector(ab, ab, 4, 5, 6, 7);
                    f32x4 h0 = mfma16(a1, b1u[0], cA1);
                    f32x4 h1 = mfma16(a1, b1u[1], cB1);
                    acc0 = mfma16(relupack(h0), b2, acc0);
                    acc1 = mfma16(relupack(h1), b2, acc1);
                }
                cA0 = nA0; cB0 = nB0; cA1 = nA1; cB1 = nB1;
            }

            #pragma unroll
            for (int u = 0; u < 2; ++u) {
                const int jr = jbase + (pr * 2 + u) * 16 + g * 4;
                const f32x4 accu = u ? acc1 : acc0;
                #pragma unroll
                for (int r = 0; r < 4; ++r)
                    sM[(jr + r) * 16 + c] = (f16)(accu[r] + b2e_c);
            }
        }
    }
    __syncthreads();

    // ================= Phase 2: coor MLP via MFMA =================
    f16x8 aW[4];
    f32x4 b1cL[4], w2cL[4];
    #pragma unroll
    for (int T = 0; T < 4; ++T) {
        aW[T] = *(const f16x8*)(W1CB + (T * 16 + c) * 32 + g * 8);
        b1cL[T] = *(const f32x4*)(b1c + T * 16 + g * 4);
        w2cL[T] = *(const f32x4*)(w2c + T * 16 + g * 4);
    }
    const float b2c0 = b2cv[0];

    float cax = 0.f, cay = 0.f, caz = 0.f;
    float macc8[8] = {0.f,0.f,0.f,0.f,0.f,0.f,0.f,0.f};

    #pragma unroll 1
    for (int jt = 0; jt < 8; ++jt) {
        const int jrow = wv * 128 + jt * 16;
        f16x8 bm = {0,0,0,0,0,0,0,0};
        if (g < 2) {
            bm = *(const f16x8*)(sM + (jrow + c) * 16 + g * 8);
            #pragma unroll
            for (int p = 0; p < 8; ++p) macc8[p] += (float)bm[p];
        }
        f32x4 zc = {0,0,0,0};
        float cwp = 0.f;
        #pragma unroll
        for (int T = 0; T < 4; ++T) {
            f32x4 hd = __builtin_amdgcn_mfma_f32_16x16x32_f16(aW[T], bm, zc, 0, 0, 0);
            #pragma unroll
            for (int r = 0; r < 4; ++r)
                cwp += fmaxf(hd[r] + b1cL[T][r], 0.f) * w2cL[T][r];
        }
        cwp += __shfl_xor(cwp, 16);
        cwp += __shfl_xor(cwp, 32);
        float cw = cwp + b2c0;

        int jg = (bb << 9) + jrow + c;
        float rx = cix - coors[jg * 3 + 0];
        float ry = ciy - coors[jg * 3 + 1];
        float rz = ciz - coors[jg * 3 + 2];
        cax += cw * rx; cay += cw * ry; caz += cw * rz;
    }

    // m_i: reduce macc8 over the 16 c-lanes (butterfly)
    #pragma unroll
    for (int msk = 1; msk <= 8; msk <<= 1)
        #pragma unroll
        for (int p = 0; p < 8; ++p) macc8[p] += __shfl_xor(macc8[p], msk);
    if (c == 0 && g < 2) {
        #pragma unroll
        for (int p = 0; p < 8; ++p) sRedM[wv][g * 8 + p] = macc8[p];
    }
    // coors: full-wave reduce (each edge counted 4x -> scale 0.25 at the end)
    #pragma unroll
    for (int msk = 1; msk <= 32; msk <<= 1) {
        cax += __shfl_xor(cax, msk);
        cay += __shfl_xor(cay, msk);
        caz += __shfl_xor(caz, msk);
    }
    if (lane == 0) { sRedC[wv][0] = cax; sRedC[wv][1] = cay; sRedC[wv][2] = caz; }
    __syncthreads();

    if (t < 16) sFin[t] = sRedM[0][t] + sRedM[1][t] + sRedM[2][t] + sRedM[3][t];
    if (t >= 32 && t < 35) {
        int k = t - 32;
        out[OUT_H + bi * 3 + k] =
            (sRedC[0][k] + sRedC[1][k] + sRedC[2][k] + sRedC[3][k]) * 0.25f;
    }
    __syncthreads();

    // ================= node MLP =================
    if (t < 128) {
        float a = b1h[t];
        const float* fp = feats + bi * 64;
        #pragma unroll 8
        for (int k = 0; k < 64; ++k) a += fp[k] * w1h[k * 128 + t];
        #pragma unroll
        for (int k = 0; k < 16; ++k) a += sFin[k] * w1h[(64 + k) * 128 + t];
        sHid[t] = fmaxf(a, 0.f);
    }
    __syncthreads();
    if (t < 64) {
        float a = b2h[t];
        #pragma unroll 8
        for (int k = 0; k < 128; ++k) a += sHid[k] * w2h[k * 64 + t];
        out[bi * 64 + t] = a;
    }
}

extern "C" void kernel_launch(void* const* d_in, const int* in_sizes, int n_in,
                              void* d_out, int out_size, void* d_ws, size_t ws_size,
                              hipStream_t stream)
{
    const float* feats = (const float*)d_in[0];
    const float* coors = (const float*)d_in[1];
    const float* w1e   = (const float*)d_in[2];
    const float* b1e   = (const float*)d_in[3];
    const float* w2e   = (const float*)d_in[4];
    const float* b2e   = (const float*)d_in[5];
    const float* w1c   = (const float*)d_in[6];
    const float* b1c   = (const float*)d_in[7];
    const float* w2c   = (const float*)d_in[8];
    const float* b2c   = (const float*)d_in[9];
    const float* w1h   = (const float*)d_in[10];
    const float* b1h   = (const float*)d_in[11];
    const float* w2h   = (const float*)d_in[12];
    const float* b2h   = (const float*)d_in[13];
    float* out = (float*)d_out;

    char* ws = (char*)d_ws;
    f16*   Q1   = (f16*)ws;                                  // 589824 B
    float* P2   = (float*)(ws + 589824);                     // 1179648 B
    f16*   Wd   = (f16*)(ws + 589824 + 1179648);             // 5184 B
    f16*   W2F  = (f16*)(ws + 589824 + 1179648 + 5184);      // 9216 B
    f16*   W1CB = (f16*)(ws + 589824 + 1179648 + 5184 + 9216); // 4096 B

    egnn_pre<<<2327, 256, 0, stream>>>(feats, w1e, b1e, w2e, w1c, Q1, P2, Wd, W2F, W1CB);
    egnn_edge<<<1024, 256, 0, stream>>>(feats, coors, b2e, b1c, w2c, b2c,
                                        w1h, b1h, w2h, b2h,
                                        Q1, P2, Wd, W2F, W1CB, out);
}

// Round 9
// 75.253 us; speedup vs baseline: 1.3870x; 1.3870x over previous
//
#include <hip/hip_runtime.h>
#include <math.h>
#include <stdint.h>

#define NP 288               // 274 padded to 18*16
#define OUT_H (2*512*64)

typedef _Float16 f16;
typedef __attribute__((ext_vector_type(2))) _Float16 f16x2;
typedef __attribute__((ext_vector_type(4))) _Float16 f16x4;
typedef __attribute__((ext_vector_type(8))) _Float16 f16x8;
typedef __attribute__((ext_vector_type(4))) float f32x4;

static __device__ __forceinline__ f16x2 pkrtz(float a, float b) {
    return __builtin_bit_cast(f16x2, __builtin_amdgcn_cvt_pkrtz(a, b));
}

#if defined(__has_builtin)
#if __has_builtin(__builtin_amdgcn_mfma_f32_16x16x16f16)
#define HAVE_MFMA16 1
#endif
#endif

static __device__ __forceinline__ f32x4 mfma16(f16x4 a, f16x4 b, f32x4 c) {
#ifdef HAVE_MFMA16
    return __builtin_amdgcn_mfma_f32_16x16x16f16(a, b, c, 0, 0, 0);
#else
    f32x4 d;
    asm volatile("v_mfma_f32_16x16x16_f16 %0, %1, %2, %3\n\ts_nop 7\n\ts_nop 7"
                 : "=v"(d) : "v"(a), "v"(b), "v"(c));
    return d;
#endif
}

// relu + pack f32x4 -> f16x4 (pkrtz monotone & exact at 0 -> pack-then-max ok)
static __device__ __forceinline__ f16x4 relupack(f32x4 h) {
    f16x2 lo = pkrtz(h[0], h[1]);
    f16x2 hi = pkrtz(h[2], h[3]);
    const f16x2 z = {(_Float16)0, (_Float16)0};
    lo = __builtin_elementwise_max(lo, z);
    hi = __builtin_elementwise_max(hi, z);
    return __builtin_shufflevector(lo, hi, 0, 1, 2, 3);
}

// ---------------------------------------------------------------------------
// Kernel A: precompute (all f16, e-padded to 288 with zeros)
//   Q1[n][288]     = b1e + feats[n] @ w1e[0:64]    (i-side, includes bias)
//   P2[n][288]     = feats[n] @ w1e[64:128]        (j-side)
//   Wd[9][288]     = w1e[128+k]                    (dist-enc rows)
//   W2F[18][64]x4  = per-lane B2 fragments: W2F[S][c+16g][jj] = w2e[S*16+g*4+jj][c]
//   W1CB[4][16][32]= w1c[k][16T+c] (k<16, else 0)  (coor-MLP A-frag source)
// ---------------------------------------------------------------------------
__global__ __launch_bounds__(256) void egnn_pre(
    const float* __restrict__ feats, const float* __restrict__ w1e,
    const float* __restrict__ b1e,   const float* __restrict__ w2e,
    const float* __restrict__ w1c,
    f16* __restrict__ Q1, f16* __restrict__ P2, f16* __restrict__ Wd,
    f16* __restrict__ W2F, f16* __restrict__ W1CB)
{
    int id = blockIdx.x * 256 + threadIdx.x;
    const int NN = 1024 * NP;
    if (id < 2 * NN) {
        int hf = id / NN, r = id % NN;
        int n = r / NP, e = r % NP;
        float a = 0.f;
        if (e < 274) {
            a = hf ? 0.f : b1e[e];
            const float* fp = feats + n * 64;
            const float* wp = w1e + hf * 64 * 274 + e;
            #pragma unroll 8
            for (int d2 = 0; d2 < 64; ++d2) a += fp[d2] * wp[d2 * 274];
        }
        (hf ? P2 : Q1)[n * NP + e] = (f16)a;
    } else {
        int x = id - 2 * NN;
        if (x < 9 * NP) {
            int e = x % NP, k = x / NP;
            Wd[x] = (f16)(e < 274 ? w1e[(128 + k) * 274 + e] : 0.f);
        } else if (x < 9 * NP + 1152) {
            int y = x - 9 * NP;                  // 0..1151
            int S = y >> 6, l = y & 63, cc = l & 15, gg = l >> 4;
            f16x4 v = {0, 0, 0, 0};
            #pragma unroll
            for (int jj = 0; jj < 4; ++jj) {
                int e = S * 16 + gg * 4 + jj;
                v[jj] = (f16)(e < 274 ? w2e[e * 16 + cc] : 0.f);
            }
            *(f16x4*)(W2F + y * 4) = v;
        } else if (x < 9 * NP + 1152 + 2048) {
            int y = x - 9 * NP - 1152;           // 0..2047
            int T = y >> 9, rem = y & 511, c2 = rem >> 5, k = rem & 31;
            W1CB[y] = (f16)(k < 16 ? w1c[k * 64 + T * 16 + c2] : 0.f);
        }
    }
}

// ---------------------------------------------------------------------------
// Kernel B: one block per (b,i). 4 waves x 128 j each.
// Phase 1: 2-unit ILP, S in pairs, 3-generation static prefetch (S..S+5 in
//   flight -> ~2 iterations ~300+ cyc ahead of use; all names static).
//   Per (unit,S): D1 = WdAug(A) x encAug(B) + P2(C) [= pre^T tile],
//   relu+pack -> A-frag of  m += H(A) x w2e^T(B).
// Phase 2: coor MLP via MFMA, reductions, node MLP.
// ---------------------------------------------------------------------------
__global__ __launch_bounds__(256) void egnn_edge(
    const float* __restrict__ feats, const float* __restrict__ coors,
    const float* __restrict__ b2e,   const float* __restrict__ b1c,
    const float* __restrict__ w2c,   const float* __restrict__ b2cv,
    const float* __restrict__ w1h,   const float* __restrict__ b1h,
    const float* __restrict__ w2h,   const float* __restrict__ b2h,
    const f16* __restrict__ Q1,  const f16* __restrict__ P2,
    const f16* __restrict__ Wd,  const f16* __restrict__ W2F,
    const f16* __restrict__ W1CB, float* __restrict__ out)
{
    __shared__ f16x4 sA1f[1152];        // 9216 B: A1 frags (Wd rows + Q1 in k=9)
    __shared__ f16x4 sB2f[1152];        // 9216 B: B2 frags (w2e^T)
    __shared__ __align__(16) f16 sM[512 * 16];   // 16384 B: m_ij
    __shared__ float sHid[128];
    __shared__ float sRedM[4][16];
    __shared__ float sRedC[4][3];
    __shared__ float sFin[16];

    const int bi = blockIdx.x, bb = bi >> 9;
    const int t = threadIdx.x;
    const int lane = t & 63, wv = t >> 6;
    const int c = lane & 15, g = lane >> 4;

    // ---- block init: stage B2 frags, build A1 frags (fold Q1 into k=9) ----
    {
        const uint2* src = (const uint2*)W2F;
        uint2* dst = (uint2*)sB2f;
        for (int x = t; x < 1152; x += 256) dst[x] = src[x];
        const f16* Q1r = Q1 + bi * NP;
        for (int x = t; x < 1152; x += 256) {
            int S = x >> 6, l = x & 63, cc = l & 15, gg = l >> 4;
            int e = S * 16 + cc;
            f16x4 v = {0, 0, 0, 0};
            if (gg == 0)      { v[0]=Wd[0*NP+e]; v[1]=Wd[1*NP+e]; v[2]=Wd[2*NP+e]; v[3]=Wd[3*NP+e]; }
            else if (gg == 1) { v[0]=Wd[4*NP+e]; v[1]=Wd[5*NP+e]; v[2]=Wd[6*NP+e]; v[3]=Wd[7*NP+e]; }
            else if (gg == 2) { v[0]=Wd[8*NP+e]; v[1]=Q1r[e]; }
            sA1f[x] = v;
        }
    }
    const float b2e_c = b2e[c];
    const float cix = coors[bi * 3 + 0];
    const float ciy = coors[bi * 3 + 1];
    const float ciz = coors[bi * 3 + 2];
    __syncthreads();

    const f16* P2b = P2 + (bb << 9) * NP;

    // ================= Phase 1: edge MLP, 2-unit ILP + 3-gen prefetch =======
    #pragma unroll 1
    for (int pass = 0; pass < 2; ++pass) {
        const int jbase = wv * 128 + pass * 64;
        #pragma unroll 1
        for (int pr = 0; pr < 2; ++pr) {
            f16x4 b1u[2];
            const f16* cpp[2];
            #pragma unroll
            for (int u = 0; u < 2; ++u) {
                const int j = jbase + (pr * 2 + u) * 16 + c;
                const int jg = (bb << 9) + j;
                float rx = cix - coors[jg * 3 + 0];
                float ry = ciy - coors[jg * 3 + 1];
                float rz = ciz - coors[jg * 3 + 2];
                float sq = rx * rx + ry * ry + rz * rz;
                float d = sq > 0.f ? sqrtf(sq) : 0.f;
                float en[8];
                #pragma unroll
                for (int k = 0; k < 4; ++k)
                    __sincosf(d * (1.f / (float)(1 << k)), &en[k], &en[4 + k]);
                f16x2 p01 = pkrtz(en[0], en[1]);
                f16x2 p23 = pkrtz(en[2], en[3]);
                f16x2 p45 = pkrtz(en[4], en[5]);
                f16x2 p67 = pkrtz(en[6], en[7]);
                f16x2 pd1 = pkrtz(d, 1.0f);
                f16x2 zz = {(_Float16)0, (_Float16)0};
                f16x2 lo = (g == 0) ? p01 : (g == 1) ? p45 : (g == 2) ? pd1 : zz;
                f16x2 hi = (g == 0) ? p23 : (g == 1) ? p67 : zz;
                b1u[u] = __builtin_shufflevector(lo, hi, 0, 1, 2, 3);
                cpp[u] = P2b + j * NP + g * 4;
            }

            f32x4 acc0 = {0,0,0,0}, acc1 = {0,0,0,0};
            // 3-generation prologue: C-frags for S=0..5 (both units)
            f16x4 c0A = *(const f16x4*)(cpp[0]);
            f16x4 c0B = *(const f16x4*)(cpp[1]);
            f16x4 c1A = *(const f16x4*)(cpp[0] + 16);
            f16x4 c1B = *(const f16x4*)(cpp[1] + 16);
            f16x4 n0A = *(const f16x4*)(cpp[0] + 32);
            f16x4 n0B = *(const f16x4*)(cpp[1] + 32);
            f16x4 n1A = *(const f16x4*)(cpp[0] + 48);
            f16x4 n1B = *(const f16x4*)(cpp[1] + 48);

            #pragma unroll
            for (int S2 = 0; S2 < 9; ++S2) {
                const int S = 2 * S2;
                f16x4 m0A = c0A, m0B = c0B, m1A = c1A, m1B = c1B;
                if (S2 < 7) {
                    m0A = *(const f16x4*)(cpp[0] + (S + 4) * 16);
                    m0B = *(const f16x4*)(cpp[1] + (S + 4) * 16);
                    m1A = *(const f16x4*)(cpp[0] + (S + 5) * 16);
                    m1B = *(const f16x4*)(cpp[1] + (S + 5) * 16);
                }
                // ---- step S ----
                {
                    f16x4 a1 = sA1f[S * 64 + lane];
                    f16x4 b2 = sB2f[S * 64 + lane];
                    f32x4 cf0 = {(float)c0A[0], (float)c0A[1], (float)c0A[2], (float)c0A[3]};
                    f32x4 cf1 = {(float)c0B[0], (float)c0B[1], (float)c0B[2], (float)c0B[3]};
                    f32x4 h0 = mfma16(a1, b1u[0], cf0);
                    f32x4 h1 = mfma16(a1, b1u[1], cf1);
                    acc0 = mfma16(relupack(h0), b2, acc0);
                    acc1 = mfma16(relupack(h1), b2, acc1);
                }
                // ---- step S+1 ----
                {
                    f16x4 a1 = sA1f[(S + 1) * 64 + lane];
                    f16x4 b2 = sB2f[(S + 1) * 64 + lane];
                    f32x4 cf0 = {(float)c1A[0], (float)c1A[1], (float)c1A[2], (float)c1A[3]};
                    f32x4 cf1 = {(float)c1B[0], (float)c1B[1], (float)c1B[2], (float)c1B[3]};
                    f32x4 h0 = mfma16(a1, b1u[0], cf0);
                    f32x4 h1 = mfma16(a1, b1u[1], cf1);
                    acc0 = mfma16(relupack(h0), b2, acc0);
                    acc1 = mfma16(relupack(h1), b2, acc1);
                }
                c0A = n0A; c0B = n0B; c1A = n1A; c1B = n1B;
                n0A = m0A; n0B = m0B; n1A = m1A; n1B = m1B;
            }

            #pragma unroll
            for (int u = 0; u < 2; ++u) {
                const int jr = jbase + (pr * 2 + u) * 16 + g * 4;
                const f32x4 accu = u ? acc1 : acc0;
                #pragma unroll
                for (int r = 0; r < 4; ++r)
                    sM[(jr + r) * 16 + c] = (f16)(accu[r] + b2e_c);
            }
        }
    }
    __syncthreads();

    // ================= Phase 2: coor MLP via MFMA =================
    f16x8 aW[4];
    f32x4 b1cL[4], w2cL[4];
    #pragma unroll
    for (int T = 0; T < 4; ++T) {
        aW[T] = *(const f16x8*)(W1CB + (T * 16 + c) * 32 + g * 8);
        b1cL[T] = *(const f32x4*)(b1c + T * 16 + g * 4);
        w2cL[T] = *(const f32x4*)(w2c + T * 16 + g * 4);
    }
    const float b2c0 = b2cv[0];

    float cax = 0.f, cay = 0.f, caz = 0.f;
    float macc8[8] = {0.f,0.f,0.f,0.f,0.f,0.f,0.f,0.f};

    #pragma unroll 1
    for (int jt = 0; jt < 8; ++jt) {
        const int jrow = wv * 128 + jt * 16;
        f16x8 bm = {0,0,0,0,0,0,0,0};
        if (g < 2) {
            bm = *(const f16x8*)(sM + (jrow + c) * 16 + g * 8);
            #pragma unroll
            for (int p = 0; p < 8; ++p) macc8[p] += (float)bm[p];
        }
        f32x4 zc = {0,0,0,0};
        float cwp = 0.f;
        #pragma unroll
        for (int T = 0; T < 4; ++T) {
            f32x4 hd = __builtin_amdgcn_mfma_f32_16x16x32_f16(aW[T], bm, zc, 0, 0, 0);
            #pragma unroll
            for (int r = 0; r < 4; ++r)
                cwp += fmaxf(hd[r] + b1cL[T][r], 0.f) * w2cL[T][r];
        }
        cwp += __shfl_xor(cwp, 16);
        cwp += __shfl_xor(cwp, 32);
        float cw = cwp + b2c0;

        int jg = (bb << 9) + jrow + c;
        float rx = cix - coors[jg * 3 + 0];
        float ry = ciy - coors[jg * 3 + 1];
        float rz = ciz - coors[jg * 3 + 2];
        cax += cw * rx; cay += cw * ry; caz += cw * rz;
    }

    // m_i: reduce macc8 over the 16 c-lanes (butterfly)
    #pragma unroll
    for (int msk = 1; msk <= 8; msk <<= 1)
        #pragma unroll
        for (int p = 0; p < 8; ++p) macc8[p] += __shfl_xor(macc8[p], msk);
    if (c == 0 && g < 2) {
        #pragma unroll
        for (int p = 0; p < 8; ++p) sRedM[wv][g * 8 + p] = macc8[p];
    }
    // coors: full-wave reduce (each edge counted 4x -> scale 0.25 at the end)
    #pragma unroll
    for (int msk = 1; msk <= 32; msk <<= 1) {
        cax += __shfl_xor(cax, msk);
        cay += __shfl_xor(cay, msk);
        caz += __shfl_xor(caz, msk);
    }
    if (lane == 0) { sRedC[wv][0] = cax; sRedC[wv][1] = cay; sRedC[wv][2] = caz; }
    __syncthreads();

    if (t < 16) sFin[t] = sRedM[0][t] + sRedM[1][t] + sRedM[2][t] + sRedM[3][t];
    if (t >= 32 && t < 35) {
        int k = t - 32;
        out[OUT_H + bi * 3 + k] =
            (sRedC[0][k] + sRedC[1][k] + sRedC[2][k] + sRedC[3][k]) * 0.25f;
    }
    __syncthreads();

    // ================= node MLP =================
    if (t < 128) {
        float a = b1h[t];
        const float* fp = feats + bi * 64;
        #pragma unroll 8
        for (int k = 0; k < 64; ++k) a += fp[k] * w1h[k * 128 + t];
        #pragma unroll
        for (int k = 0; k < 16; ++k) a += sFin[k] * w1h[(64 + k) * 128 + t];
        sHid[t] = fmaxf(a, 0.f);
    }
    __syncthreads();
    if (t < 64) {
        float a = b2h[t];
        #pragma unroll 8
        for (int k = 0; k < 128; ++k) a += sHid[k] * w2h[k * 64 + t];
        out[bi * 64 + t] = a;
    }
}

extern "C" void kernel_launch(void* const* d_in, const int* in_sizes, int n_in,
                              void* d_out, int out_size, void* d_ws, size_t ws_size,
                              hipStream_t stream)
{
    const float* feats = (const float*)d_in[0];
    const float* coors = (const float*)d_in[1];
    const float* w1e   = (const float*)d_in[2];
    const float* b1e   = (const float*)d_in[3];
    const float* w2e   = (const float*)d_in[4];
    const float* b2e   = (const float*)d_in[5];
    const float* w1c   = (const float*)d_in[6];
    const float* b1c   = (const float*)d_in[7];
    const float* w2c   = (const float*)d_in[8];
    const float* b2c   = (const float*)d_in[9];
    const float* w1h   = (const float*)d_in[10];
    const float* b1h   = (const float*)d_in[11];
    const float* w2h   = (const float*)d_in[12];
    const float* b2h   = (const float*)d_in[13];
    float* out = (float*)d_out;

    char* ws = (char*)d_ws;
    f16* Q1   = (f16*)ws;                               // 589824 B
    f16* P2   = (f16*)(ws + 589824);                    // 589824 B
    f16* Wd   = (f16*)(ws + 1179648);                   // 5184 B
    f16* W2F  = (f16*)(ws + 1179648 + 5184);            // 9216 B
    f16* W1CB = (f16*)(ws + 1179648 + 5184 + 9216);     // 4096 B

    egnn_pre<<<2327, 256, 0, stream>>>(feats, w1e, b1e, w2e, w1c, Q1, P2, Wd, W2F, W1CB);
    egnn_edge<<<1024, 256, 0, stream>>>(feats, coors, b2e, b1c, w2c, b2c,
                                        w1h, b1h, w2h, b2h,
                                        Q1, P2, Wd, W2F, W1CB, out);
}

// Round 10
// 65.492 us; speedup vs baseline: 1.5938x; 1.1490x over previous
//
#include <hip/hip_runtime.h>
#include <math.h>
#include <stdint.h>

#define NP 288               // 274 padded to 18*16
#define OUT_H (2*512*64)

typedef _Float16 f16;
typedef __attribute__((ext_vector_type(2))) _Float16 f16x2;
typedef __attribute__((ext_vector_type(4))) _Float16 f16x4;
typedef __attribute__((ext_vector_type(8))) _Float16 f16x8;
typedef __attribute__((ext_vector_type(4))) float f32x4;

static __device__ __forceinline__ f16x2 pkrtz(float a, float b) {
    return __builtin_bit_cast(f16x2, __builtin_amdgcn_cvt_pkrtz(a, b));
}

#if defined(__has_builtin)
#if __has_builtin(__builtin_amdgcn_mfma_f32_16x16x16f16)
#define HAVE_MFMA16 1
#endif
#endif

static __device__ __forceinline__ f32x4 mfma16(f16x4 a, f16x4 b, f32x4 c) {
#ifdef HAVE_MFMA16
    return __builtin_amdgcn_mfma_f32_16x16x16f16(a, b, c, 0, 0, 0);
#else
    f32x4 d;
    asm volatile("v_mfma_f32_16x16x16_f16 %0, %1, %2, %3\n\ts_nop 7\n\ts_nop 7"
                 : "=v"(d) : "v"(a), "v"(b), "v"(c));
    return d;
#endif
}

// relu + pack f32x4 -> f16x4 (pkrtz monotone & exact at 0 -> pack-then-max ok)
static __device__ __forceinline__ f16x4 relupack(f32x4 h) {
    f16x2 lo = pkrtz(h[0], h[1]);
    f16x2 hi = pkrtz(h[2], h[3]);
    const f16x2 z = {(_Float16)0, (_Float16)0};
    lo = __builtin_elementwise_max(lo, z);
    hi = __builtin_elementwise_max(hi, z);
    return __builtin_shufflevector(lo, hi, 0, 1, 2, 3);
}

// ---------------------------------------------------------------------------
// Kernel A: precompute (all f16, e-padded to 288 with zeros)
//   Q1[n][288]  = b1e + feats[n] @ w1e[0:64]       (i-side, includes bias)
//   P2F[b][32jt][18S][64lane]x4 = C-fragment-ordered j-side projection:
//       P2F[b][jt][S][c+16g][r] = (feats[b,jt*16+c] @ w1e[64:128])[S*16+g*4+r]
//       -> kernel B's wave load of a C-frag is ONE contiguous 512-B burst.
//   Wd[9][288]     = w1e[128+k]                    (dist-enc rows)
//   W2F[18][64]x4  = per-lane B2 fragments: W2F[S][c+16g][jj] = w2e[S*16+g*4+jj][c]
//   W1CB[4][16][32]= w1c[k][16T+c] (k<16, else 0)  (coor-MLP A-frag source)
// ---------------------------------------------------------------------------
__global__ __launch_bounds__(256) void egnn_pre(
    const float* __restrict__ feats, const float* __restrict__ w1e,
    const float* __restrict__ b1e,   const float* __restrict__ w2e,
    const float* __restrict__ w1c,
    f16* __restrict__ Q1, f16* __restrict__ P2F, f16* __restrict__ Wd,
    f16* __restrict__ W2F, f16* __restrict__ W1CB)
{
    int id = blockIdx.x * 256 + threadIdx.x;
    const int NN = 1024 * NP;
    if (id < 2 * NN) {
        int hf = id / NN, r = id % NN;
        int n = r / NP, e = r % NP;
        float a = 0.f;
        if (e < 274) {
            a = hf ? 0.f : b1e[e];
            const float* fp = feats + n * 64;
            const float* wp = w1e + hf * 64 * 274 + e;
            #pragma unroll 8
            for (int d2 = 0; d2 < 64; ++d2) a += fp[d2] * wp[d2 * 274];
        }
        if (hf) {
            // fragment-order scatter: b, j=n&511 -> jt,c ; e -> S,gg,jj
            int b = n >> 9, j = n & 511;
            int jt = j >> 4, cl = j & 15;
            int S = e >> 4, gg = (e >> 2) & 3, jj = e & 3;
            P2F[(((b * 32 + jt) * 18 + S) * 64 + (cl + 16 * gg)) * 4 + jj] = (f16)a;
        } else {
            Q1[n * NP + e] = (f16)a;
        }
    } else {
        int x = id - 2 * NN;
        if (x < 9 * NP) {
            int e = x % NP, k = x / NP;
            Wd[x] = (f16)(e < 274 ? w1e[(128 + k) * 274 + e] : 0.f);
        } else if (x < 9 * NP + 1152) {
            int y = x - 9 * NP;                  // 0..1151
            int S = y >> 6, l = y & 63, cc = l & 15, gg = l >> 4;
            f16x4 v = {0, 0, 0, 0};
            #pragma unroll
            for (int jj = 0; jj < 4; ++jj) {
                int e = S * 16 + gg * 4 + jj;
                v[jj] = (f16)(e < 274 ? w2e[e * 16 + cc] : 0.f);
            }
            *(f16x4*)(W2F + y * 4) = v;
        } else if (x < 9 * NP + 1152 + 2048) {
            int y = x - 9 * NP - 1152;           // 0..2047
            int T = y >> 9, rem = y & 511, c2 = rem >> 5, k = rem & 31;
            W1CB[y] = (f16)(k < 16 ? w1c[k * 64 + T * 16 + c2] : 0.f);
        }
    }
}

// ---------------------------------------------------------------------------
// Kernel B: one block per (b,i). 4 waves x 128 j each.
// Phase 1: 2-unit ILP, S in pairs, 3-gen static prefetch; C-frags now load
//   from fragment-ordered P2F -> one coalesced 512-B wave burst per frag.
//   Per (unit,S): D1 = WdAug(A) x encAug(B) + P2(C) [= pre^T tile],
//   relu+pack -> A-frag of  m += H(A) x w2e^T(B).
// Phase 2: coor MLP via MFMA, reductions, node MLP.
// ---------------------------------------------------------------------------
__global__ __launch_bounds__(256) void egnn_edge(
    const float* __restrict__ feats, const float* __restrict__ coors,
    const float* __restrict__ b2e,   const float* __restrict__ b1c,
    const float* __restrict__ w2c,   const float* __restrict__ b2cv,
    const float* __restrict__ w1h,   const float* __restrict__ b1h,
    const float* __restrict__ w2h,   const float* __restrict__ b2h,
    const f16* __restrict__ Q1,  const f16* __restrict__ P2F,
    const f16* __restrict__ Wd,  const f16* __restrict__ W2F,
    const f16* __restrict__ W1CB, float* __restrict__ out)
{
    __shared__ f16x4 sA1f[1152];        // 9216 B: A1 frags (Wd rows + Q1 in k=9)
    __shared__ f16x4 sB2f[1152];        // 9216 B: B2 frags (w2e^T)
    __shared__ __align__(16) f16 sM[512 * 16];   // 16384 B: m_ij
    __shared__ float sHid[128];
    __shared__ float sRedM[4][16];
    __shared__ float sRedC[4][3];
    __shared__ float sFin[16];

    const int bi = blockIdx.x, bb = bi >> 9;
    const int t = threadIdx.x;
    const int lane = t & 63, wv = t >> 6;
    const int c = lane & 15, g = lane >> 4;

    // ---- block init: stage B2 frags, build A1 frags (fold Q1 into k=9) ----
    {
        const uint2* src = (const uint2*)W2F;
        uint2* dst = (uint2*)sB2f;
        for (int x = t; x < 1152; x += 256) dst[x] = src[x];
        const f16* Q1r = Q1 + bi * NP;
        for (int x = t; x < 1152; x += 256) {
            int S = x >> 6, l = x & 63, cc = l & 15, gg = l >> 4;
            int e = S * 16 + cc;
            f16x4 v = {0, 0, 0, 0};
            if (gg == 0)      { v[0]=Wd[0*NP+e]; v[1]=Wd[1*NP+e]; v[2]=Wd[2*NP+e]; v[3]=Wd[3*NP+e]; }
            else if (gg == 1) { v[0]=Wd[4*NP+e]; v[1]=Wd[5*NP+e]; v[2]=Wd[6*NP+e]; v[3]=Wd[7*NP+e]; }
            else if (gg == 2) { v[0]=Wd[8*NP+e]; v[1]=Q1r[e]; }
            sA1f[x] = v;
        }
    }
    const float b2e_c = b2e[c];
    const float cix = coors[bi * 3 + 0];
    const float ciy = coors[bi * 3 + 1];
    const float ciz = coors[bi * 3 + 2];
    __syncthreads();

    const f16* P2Fb = P2F + (bb << 5) * 18 * 256;   // [32jt][18S][256]

    // ================= Phase 1: edge MLP, 2-unit ILP + 3-gen prefetch =======
    #pragma unroll 1
    for (int pass = 0; pass < 2; ++pass) {
        const int jbase = wv * 128 + pass * 64;
        #pragma unroll 1
        for (int pr = 0; pr < 2; ++pr) {
            f16x4 b1u[2];
            const f16* cpp[2];
            #pragma unroll
            for (int u = 0; u < 2; ++u) {
                const int jt = (jbase >> 4) + pr * 2 + u;
                const int j = jbase + (pr * 2 + u) * 16 + c;
                const int jg = (bb << 9) + j;
                float rx = cix - coors[jg * 3 + 0];
                float ry = ciy - coors[jg * 3 + 1];
                float rz = ciz - coors[jg * 3 + 2];
                float sq = rx * rx + ry * ry + rz * rz;
                float d = sq > 0.f ? sqrtf(sq) : 0.f;
                float en[8];
                #pragma unroll
                for (int k = 0; k < 4; ++k)
                    __sincosf(d * (1.f / (float)(1 << k)), &en[k], &en[4 + k]);
                f16x2 p01 = pkrtz(en[0], en[1]);
                f16x2 p23 = pkrtz(en[2], en[3]);
                f16x2 p45 = pkrtz(en[4], en[5]);
                f16x2 p67 = pkrtz(en[6], en[7]);
                f16x2 pd1 = pkrtz(d, 1.0f);
                f16x2 zz = {(_Float16)0, (_Float16)0};
                f16x2 lo = (g == 0) ? p01 : (g == 1) ? p45 : (g == 2) ? pd1 : zz;
                f16x2 hi = (g == 0) ? p23 : (g == 1) ? p67 : zz;
                b1u[u] = __builtin_shufflevector(lo, hi, 0, 1, 2, 3);
                cpp[u] = P2Fb + jt * 18 * 256 + lane * 4;   // frag base, +S*256/step
            }

            f32x4 acc0 = {0,0,0,0}, acc1 = {0,0,0,0};
            // 3-generation prologue: C-frags for S=0..5 (both units)
            f16x4 c0A = *(const f16x4*)(cpp[0]);
            f16x4 c0B = *(const f16x4*)(cpp[1]);
            f16x4 c1A = *(const f16x4*)(cpp[0] + 256);
            f16x4 c1B = *(const f16x4*)(cpp[1] + 256);
            f16x4 n0A = *(const f16x4*)(cpp[0] + 512);
            f16x4 n0B = *(const f16x4*)(cpp[1] + 512);
            f16x4 n1A = *(const f16x4*)(cpp[0] + 768);
            f16x4 n1B = *(const f16x4*)(cpp[1] + 768);

            #pragma unroll
            for (int S2 = 0; S2 < 9; ++S2) {
                const int S = 2 * S2;
                f16x4 m0A = c0A, m0B = c0B, m1A = c1A, m1B = c1B;
                if (S2 < 7) {
                    m0A = *(const f16x4*)(cpp[0] + (S + 4) * 256);
                    m0B = *(const f16x4*)(cpp[1] + (S + 4) * 256);
                    m1A = *(const f16x4*)(cpp[0] + (S + 5) * 256);
                    m1B = *(const f16x4*)(cpp[1] + (S + 5) * 256);
                }
                // ---- step S ----
                {
                    f16x4 a1 = sA1f[S * 64 + lane];
                    f16x4 b2 = sB2f[S * 64 + lane];
                    f32x4 cf0 = {(float)c0A[0], (float)c0A[1], (float)c0A[2], (float)c0A[3]};
                    f32x4 cf1 = {(float)c0B[0], (float)c0B[1], (float)c0B[2], (float)c0B[3]};
                    f32x4 h0 = mfma16(a1, b1u[0], cf0);
                    f32x4 h1 = mfma16(a1, b1u[1], cf1);
                    acc0 = mfma16(relupack(h0), b2, acc0);
                    acc1 = mfma16(relupack(h1), b2, acc1);
                }
                // ---- step S+1 ----
                {
                    f16x4 a1 = sA1f[(S + 1) * 64 + lane];
                    f16x4 b2 = sB2f[(S + 1) * 64 + lane];
                    f32x4 cf0 = {(float)c1A[0], (float)c1A[1], (float)c1A[2], (float)c1A[3]};
                    f32x4 cf1 = {(float)c1B[0], (float)c1B[1], (float)c1B[2], (float)c1B[3]};
                    f32x4 h0 = mfma16(a1, b1u[0], cf0);
                    f32x4 h1 = mfma16(a1, b1u[1], cf1);
                    acc0 = mfma16(relupack(h0), b2, acc0);
                    acc1 = mfma16(relupack(h1), b2, acc1);
                }
                c0A = n0A; c0B = n0B; c1A = n1A; c1B = n1B;
                n0A = m0A; n0B = m0B; n1A = m1A; n1B = m1B;
            }

            #pragma unroll
            for (int u = 0; u < 2; ++u) {
                const int jr = jbase + (pr * 2 + u) * 16 + g * 4;
                const f32x4 accu = u ? acc1 : acc0;
                #pragma unroll
                for (int r = 0; r < 4; ++r)
                    sM[(jr + r) * 16 + c] = (f16)(accu[r] + b2e_c);
            }
        }
    }
    __syncthreads();

    // ================= Phase 2: coor MLP via MFMA =================
    f16x8 aW[4];
    f32x4 b1cL[4], w2cL[4];
    #pragma unroll
    for (int T = 0; T < 4; ++T) {
        aW[T] = *(const f16x8*)(W1CB + (T * 16 + c) * 32 + g * 8);
        b1cL[T] = *(const f32x4*)(b1c + T * 16 + g * 4);
        w2cL[T] = *(const f32x4*)(w2c + T * 16 + g * 4);
    }
    const float b2c0 = b2cv[0];

    float cax = 0.f, cay = 0.f, caz = 0.f;
    float macc8[8] = {0.f,0.f,0.f,0.f,0.f,0.f,0.f,0.f};

    #pragma unroll 1
    for (int jt = 0; jt < 8; ++jt) {
        const int jrow = wv * 128 + jt * 16;
        f16x8 bm = {0,0,0,0,0,0,0,0};
        if (g < 2) {
            bm = *(const f16x8*)(sM + (jrow + c) * 16 + g * 8);
            #pragma unroll
            for (int p = 0; p < 8; ++p) macc8[p] += (float)bm[p];
        }
        f32x4 zc = {0,0,0,0};
        float cwp = 0.f;
        #pragma unroll
        for (int T = 0; T < 4; ++T) {
            f32x4 hd = __builtin_amdgcn_mfma_f32_16x16x32_f16(aW[T], bm, zc, 0, 0, 0);
            #pragma unroll
            for (int r = 0; r < 4; ++r)
                cwp += fmaxf(hd[r] + b1cL[T][r], 0.f) * w2cL[T][r];
        }
        cwp += __shfl_xor(cwp, 16);
        cwp += __shfl_xor(cwp, 32);
        float cw = cwp + b2c0;

        int jg = (bb << 9) + jrow + c;
        float rx = cix - coors[jg * 3 + 0];
        float ry = ciy - coors[jg * 3 + 1];
        float rz = ciz - coors[jg * 3 + 2];
        cax += cw * rx; cay += cw * ry; caz += cw * rz;
    }

    // m_i: reduce macc8 over the 16 c-lanes (butterfly)
    #pragma unroll
    for (int msk = 1; msk <= 8; msk <<= 1)
        #pragma unroll
        for (int p = 0; p < 8; ++p) macc8[p] += __shfl_xor(macc8[p], msk);
    if (c == 0 && g < 2) {
        #pragma unroll
        for (int p = 0; p < 8; ++p) sRedM[wv][g * 8 + p] = macc8[p];
    }
    // coors: full-wave reduce (each edge counted 4x -> scale 0.25 at the end)
    #pragma unroll
    for (int msk = 1; msk <= 32; msk <<= 1) {
        cax += __shfl_xor(cax, msk);
        cay += __shfl_xor(cay, msk);
        caz += __shfl_xor(caz, msk);
    }
    if (lane == 0) { sRedC[wv][0] = cax; sRedC[wv][1] = cay; sRedC[wv][2] = caz; }
    __syncthreads();

    if (t < 16) sFin[t] = sRedM[0][t] + sRedM[1][t] + sRedM[2][t] + sRedM[3][t];
    if (t >= 32 && t < 35) {
        int k = t - 32;
        out[OUT_H + bi * 3 + k] =
            (sRedC[0][k] + sRedC[1][k] + sRedC[2][k] + sRedC[3][k]) * 0.25f;
    }
    __syncthreads();

    // ================= node MLP =================
    if (t < 128) {
        float a = b1h[t];
        const float* fp = feats + bi * 64;
        #pragma unroll 8
        for (int k = 0; k < 64; ++k) a += fp[k] * w1h[k * 128 + t];
        #pragma unroll
        for (int k = 0; k < 16; ++k) a += sFin[k] * w1h[(64 + k) * 128 + t];
        sHid[t] = fmaxf(a, 0.f);
    }
    __syncthreads();
    if (t < 64) {
        float a = b2h[t];
        #pragma unroll 8
        for (int k = 0; k < 128; ++k) a += sHid[k] * w2h[k * 64 + t];
        out[bi * 64 + t] = a;
    }
}

extern "C" void kernel_launch(void* const* d_in, const int* in_sizes, int n_in,
                              void* d_out, int out_size, void* d_ws, size_t ws_size,
                              hipStream_t stream)
{
    const float* feats = (const float*)d_in[0];
    const float* coors = (const float*)d_in[1];
    const float* w1e   = (const float*)d_in[2];
    const float* b1e   = (const float*)d_in[3];
    const float* w2e   = (const float*)d_in[4];
    const float* b2e   = (const float*)d_in[5];
    const float* w1c   = (const float*)d_in[6];
    const float* b1c   = (const float*)d_in[7];
    const float* w2c   = (const float*)d_in[8];
    const float* b2c   = (const float*)d_in[9];
    const float* w1h   = (const float*)d_in[10];
    const float* b1h   = (const float*)d_in[11];
    const float* w2h   = (const float*)d_in[12];
    const float* b2h   = (const float*)d_in[13];
    float* out = (float*)d_out;

    char* ws = (char*)d_ws;
    f16* Q1   = (f16*)ws;                               // 589824 B
    f16* P2F  = (f16*)(ws + 589824);                    // 589824 B (frag order)
    f16* Wd   = (f16*)(ws + 1179648);                   // 5184 B
    f16* W2F  = (f16*)(ws + 1179648 + 5184);            // 9216 B
    f16* W1CB = (f16*)(ws + 1179648 + 5184 + 9216);     // 4096 B

    egnn_pre<<<2327, 256, 0, stream>>>(feats, w1e, b1e, w2e, w1c, Q1, P2F, Wd, W2F, W1CB);
    egnn_edge<<<1024, 256, 0, stream>>>(feats, coors, b2e, b1c, w2c, b2c,
                                        w1h, b1h, w2h, b2h,
                                        Q1, P2F, Wd, W2F, W1CB, out);
}

// Round 12
// 64.571 us; speedup vs baseline: 1.6165x; 1.0143x over previous
//
#include <hip/hip_runtime.h>
#include <math.h>
#include <stdint.h>

#define NP 288               // 274 padded to 18*16
#define OUT_H (2*512*64)

typedef _Float16 f16;
typedef __attribute__((ext_vector_type(2))) _Float16 f16x2;
typedef __attribute__((ext_vector_type(4))) _Float16 f16x4;
typedef __attribute__((ext_vector_type(8))) _Float16 f16x8;
typedef __attribute__((ext_vector_type(4))) float f32x4;

static __device__ __forceinline__ f16x2 pkrtz(float a, float b) {
    return __builtin_bit_cast(f16x2, __builtin_amdgcn_cvt_pkrtz(a, b));
}

#if defined(__has_builtin)
#if __has_builtin(__builtin_amdgcn_mfma_f32_16x16x16f16)
#define HAVE_MFMA16 1
#endif
#endif

static __device__ __forceinline__ f32x4 mfma16(f16x4 a, f16x4 b, f32x4 c) {
#ifdef HAVE_MFMA16
    return __builtin_amdgcn_mfma_f32_16x16x16f16(a, b, c, 0, 0, 0);
#else
    f32x4 d;
    asm volatile("v_mfma_f32_16x16x16_f16 %0, %1, %2, %3\n\ts_nop 7\n\ts_nop 7"
                 : "=v"(d) : "v"(a), "v"(b), "v"(c));
    return d;
#endif
}

// relu + pack f32x4 -> f16x4 (pkrtz monotone & exact at 0 -> pack-then-max ok)
static __device__ __forceinline__ f16x4 relupack(f32x4 h) {
    f16x2 lo = pkrtz(h[0], h[1]);
    f16x2 hi = pkrtz(h[2], h[3]);
    const f16x2 z = {(_Float16)0, (_Float16)0};
    lo = __builtin_elementwise_max(lo, z);
    hi = __builtin_elementwise_max(hi, z);
    return __builtin_shufflevector(lo, hi, 0, 1, 2, 3);
}

// ---------------------------------------------------------------------------
// Kernel A: precompute (e-padded to 288 with zeros)
//   Q1[n][288] f16 = b1e + feats[n] @ w1e[0:64]    (i-side, includes bias)
//   P2F[b][32jt][18S][64lane]x4 f32 = C-fragment-ordered j-side projection:
//       P2F[b][jt][S][c+16g][r] = (feats[b,jt*16+c] @ w1e[64:128])[S*16+g*4+r]
//       -> wave C-frag load = ONE contiguous 1-KB burst, feeds MFMA directly.
//   Wd[9][288] f16     = w1e[128+k]                (dist-enc rows)
//   W2F[18][64]x4 f16  = per-lane B2 frags: W2F[S][c+16g][jj] = w2e[S*16+g*4+jj][c]
//   W1CB[4][16][32] f16= w1c[k][16T+c] (k<16, else 0)  (coor-MLP A-frag source)
// ---------------------------------------------------------------------------
__global__ __launch_bounds__(256) void egnn_pre(
    const float* __restrict__ feats, const float* __restrict__ w1e,
    const float* __restrict__ b1e,   const float* __restrict__ w2e,
    const float* __restrict__ w1c,
    f16* __restrict__ Q1, float* __restrict__ P2F, f16* __restrict__ Wd,
    f16* __restrict__ W2F, f16* __restrict__ W1CB)
{
    int id = blockIdx.x * 256 + threadIdx.x;
    const int NN = 1024 * NP;
    if (id < 2 * NN) {
        int hf = id / NN, r = id % NN;
        int n = r / NP, e = r % NP;
        float a = 0.f;
        if (e < 274) {
            a = hf ? 0.f : b1e[e];
            const float* fp = feats + n * 64;
            const float* wp = w1e + hf * 64 * 274 + e;
            #pragma unroll 8
            for (int d2 = 0; d2 < 64; ++d2) a += fp[d2] * wp[d2 * 274];
        }
        if (hf) {
            // fragment-order scatter: b, j=n&511 -> jt,c ; e -> S,gg,jj
            int b = n >> 9, j = n & 511;
            int jt = j >> 4, cl = j & 15;
            int S = e >> 4, gg = (e >> 2) & 3, jj = e & 3;
            P2F[(((b * 32 + jt) * 18 + S) * 64 + (cl + 16 * gg)) * 4 + jj] = a;
        } else {
            Q1[n * NP + e] = (f16)a;
        }
    } else {
        int x = id - 2 * NN;
        if (x < 9 * NP) {
            int e = x % NP, k = x / NP;
            Wd[x] = (f16)(e < 274 ? w1e[(128 + k) * 274 + e] : 0.f);
        } else if (x < 9 * NP + 1152) {
            int y = x - 9 * NP;                  // 0..1151
            int S = y >> 6, l = y & 63, cc = l & 15, gg = l >> 4;
            f16x4 v = {0, 0, 0, 0};
            #pragma unroll
            for (int jj = 0; jj < 4; ++jj) {
                int e = S * 16 + gg * 4 + jj;
                v[jj] = (f16)(e < 274 ? w2e[e * 16 + cc] : 0.f);
            }
            *(f16x4*)(W2F + y * 4) = v;
        } else if (x < 9 * NP + 1152 + 2048) {
            int y = x - 9 * NP - 1152;           // 0..2047
            int T = y >> 9, rem = y & 511, c2 = rem >> 5, k = rem & 31;
            W1CB[y] = (f16)(k < 16 ? w1c[k * 64 + T * 16 + c2] : 0.f);
        }
    }
}

// ---------------------------------------------------------------------------
// Kernel B: one block per (b,i). 4 waves x 128 j each.
// Phase 1: 2-unit ILP, S in pairs, 2-gen static prefetch of f32 C-frags
//   (coalesced 1-KB bursts, feed MFMA C directly — no cvt).
//   enc via 1 sincos + double-angle recurrence (sin2t=2sc, cos2t=1-2s^2).
//   Per (unit,S): D1 = WdAug(A) x encAug(B) + P2(C) [= pre^T tile],
//   relu+pack -> A-frag of  m += H(A) x w2e^T(B).
// Phase 2: coor MLP via MFMA, reductions, node MLP.
// ---------------------------------------------------------------------------
__global__ __launch_bounds__(256) void egnn_edge(
    const float* __restrict__ feats, const float* __restrict__ coors,
    const float* __restrict__ b2e,   const float* __restrict__ b1c,
    const float* __restrict__ w2c,   const float* __restrict__ b2cv,
    const float* __restrict__ w1h,   const float* __restrict__ b1h,
    const float* __restrict__ w2h,   const float* __restrict__ b2h,
    const f16* __restrict__ Q1,  const float* __restrict__ P2F,
    const f16* __restrict__ Wd,  const f16* __restrict__ W2F,
    const f16* __restrict__ W1CB, float* __restrict__ out)
{
    __shared__ f16x4 sA1f[1152];        // 9216 B: A1 frags (Wd rows + Q1 in k=9)
    __shared__ f16x4 sB2f[1152];        // 9216 B: B2 frags (w2e^T)
    __shared__ __align__(16) f16 sM[512 * 16];   // 16384 B: m_ij
    __shared__ float sHid[128];
    __shared__ float sRedM[4][16];
    __shared__ float sRedC[4][3];
    __shared__ float sFin[16];

    const int bi = blockIdx.x, bb = bi >> 9;
    const int t = threadIdx.x;
    const int lane = t & 63, wv = t >> 6;
    const int c = lane & 15, g = lane >> 4;

    // ---- block init: stage B2 frags, build A1 frags (fold Q1 into k=9) ----
    {
        const uint2* src = (const uint2*)W2F;
        uint2* dst = (uint2*)sB2f;
        for (int x = t; x < 1152; x += 256) dst[x] = src[x];
        const f16* Q1r = Q1 + bi * NP;
        for (int x = t; x < 1152; x += 256) {
            int S = x >> 6, l = x & 63, cc = l & 15, gg = l >> 4;
            int e = S * 16 + cc;
            f16x4 v = {0, 0, 0, 0};
            if (gg == 0)      { v[0]=Wd[0*NP+e]; v[1]=Wd[1*NP+e]; v[2]=Wd[2*NP+e]; v[3]=Wd[3*NP+e]; }
            else if (gg == 1) { v[0]=Wd[4*NP+e]; v[1]=Wd[5*NP+e]; v[2]=Wd[6*NP+e]; v[3]=Wd[7*NP+e]; }
            else if (gg == 2) { v[0]=Wd[8*NP+e]; v[1]=Q1r[e]; }
            sA1f[x] = v;
        }
    }
    const float b2e_c = b2e[c];
    const float cix = coors[bi * 3 + 0];
    const float ciy = coors[bi * 3 + 1];
    const float ciz = coors[bi * 3 + 2];
    __syncthreads();

    const float* P2Fb = P2F + (bb << 5) * 18 * 256;   // [32jt][18S][256] f32

    // ================= Phase 1: edge MLP, 2-unit ILP + 2-gen prefetch =======
    #pragma unroll 1
    for (int pass = 0; pass < 2; ++pass) {
        const int jbase = wv * 128 + pass * 64;
        #pragma unroll 1
        for (int pr = 0; pr < 2; ++pr) {
            f16x4 b1u[2];
            const float* cpp[2];
            #pragma unroll
            for (int u = 0; u < 2; ++u) {
                const int jt = (jbase >> 4) + pr * 2 + u;
                const int j = jbase + (pr * 2 + u) * 16 + c;
                const int jg = (bb << 9) + j;
                float rx = cix - coors[jg * 3 + 0];
                float ry = ciy - coors[jg * 3 + 1];
                float rz = ciz - coors[jg * 3 + 2];
                float sq = rx * rx + ry * ry + rz * rz;
                float d = sq > 0.f ? sqrtf(sq) : 0.f;
                // enc via 1 sincos + double-angle ladder (d/8 -> d/4 -> d/2 -> d)
                float s8, c8v;
                __sincosf(d * 0.125f, &s8, &c8v);
                float s4 = 2.f * s8 * c8v, c4v = 1.f - 2.f * s8 * s8;
                float s2 = 2.f * s4 * c4v, c2v = 1.f - 2.f * s4 * s4;
                float s1 = 2.f * s2 * c2v, c1v = 1.f - 2.f * s2 * s2;
                f16x2 p01 = pkrtz(s1, s2);     // sin(d), sin(d/2)
                f16x2 p23 = pkrtz(s4, s8);     // sin(d/4), sin(d/8)
                f16x2 p45 = pkrtz(c1v, c2v);   // cos(d), cos(d/2)
                f16x2 p67 = pkrtz(c4v, c8v);   // cos(d/4), cos(d/8)
                f16x2 pd1 = pkrtz(d, 1.0f);
                f16x2 zz = {(_Float16)0, (_Float16)0};
                f16x2 lo = (g == 0) ? p01 : (g == 1) ? p45 : (g == 2) ? pd1 : zz;
                f16x2 hi = (g == 0) ? p23 : (g == 1) ? p67 : zz;
                b1u[u] = __builtin_shufflevector(lo, hi, 0, 1, 2, 3);
                cpp[u] = P2Fb + jt * 18 * 256 + lane * 4;   // frag base, +S*256/step
            }

            f32x4 acc0 = {0,0,0,0}, acc1 = {0,0,0,0};
            // prologue: f32 C-frags for S=0,1 (both units)
            f32x4 c0A = *(const f32x4*)(cpp[0]);
            f32x4 c0B = *(const f32x4*)(cpp[1]);
            f32x4 c1A = *(const f32x4*)(cpp[0] + 256);
            f32x4 c1B = *(const f32x4*)(cpp[1] + 256);

            #pragma unroll
            for (int S2 = 0; S2 < 9; ++S2) {
                const int S = 2 * S2;
                f32x4 n0A, n0B, n1A, n1B;
                if (S2 < 8) {
                    n0A = *(const f32x4*)(cpp[0] + (S + 2) * 256);
                    n0B = *(const f32x4*)(cpp[1] + (S + 2) * 256);
                    n1A = *(const f32x4*)(cpp[0] + (S + 3) * 256);
                    n1B = *(const f32x4*)(cpp[1] + (S + 3) * 256);
                }
                // ---- step S ----
                {
                    f16x4 a1 = sA1f[S * 64 + lane];
                    f16x4 b2 = sB2f[S * 64 + lane];
                    f32x4 h0 = mfma16(a1, b1u[0], c0A);
                    f32x4 h1 = mfma16(a1, b1u[1], c0B);
                    acc0 = mfma16(relupack(h0), b2, acc0);
                    acc1 = mfma16(relupack(h1), b2, acc1);
                }
                // ---- step S+1 ----
                {
                    f16x4 a1 = sA1f[(S + 1) * 64 + lane];
                    f16x4 b2 = sB2f[(S + 1) * 64 + lane];
                    f32x4 h0 = mfma16(a1, b1u[0], c1A);
                    f32x4 h1 = mfma16(a1, b1u[1], c1B);
                    acc0 = mfma16(relupack(h0), b2, acc0);
                    acc1 = mfma16(relupack(h1), b2, acc1);
                }
                c0A = n0A; c0B = n0B; c1A = n1A; c1B = n1B;
            }

            #pragma unroll
            for (int u = 0; u < 2; ++u) {
                const int jr = jbase + (pr * 2 + u) * 16 + g * 4;
                const f32x4 accu = u ? acc1 : acc0;
                #pragma unroll
                for (int r = 0; r < 4; ++r)
                    sM[(jr + r) * 16 + c] = (f16)(accu[r] + b2e_c);
            }
        }
    }
    __syncthreads();

    // ================= Phase 2: coor MLP via MFMA =================
    f16x8 aW[4];
    f32x4 b1cL[4], w2cL[4];
    #pragma unroll
    for (int T = 0; T < 4; ++T) {
        aW[T] = *(const f16x8*)(W1CB + (T * 16 + c) * 32 + g * 8);
        b1cL[T] = *(const f32x4*)(b1c + T * 16 + g * 4);
        w2cL[T] = *(const f32x4*)(w2c + T * 16 + g * 4);
    }
    const float b2c0 = b2cv[0];

    float cax = 0.f, cay = 0.f, caz = 0.f;
    float macc8[8] = {0.f,0.f,0.f,0.f,0.f,0.f,0.f,0.f};

    #pragma unroll 1
    for (int jt = 0; jt < 8; ++jt) {
        const int jrow = wv * 128 + jt * 16;
        f16x8 bm = {0,0,0,0,0,0,0,0};
        if (g < 2) {
            bm = *(const f16x8*)(sM + (jrow + c) * 16 + g * 8);
            #pragma unroll
            for (int p = 0; p < 8; ++p) macc8[p] += (float)bm[p];
        }
        f32x4 zc = {0,0,0,0};
        float cwp = 0.f;
        #pragma unroll
        for (int T = 0; T < 4; ++T) {
            f32x4 hd = __builtin_amdgcn_mfma_f32_16x16x32_f16(aW[T], bm, zc, 0, 0, 0);
            #pragma unroll
            for (int r = 0; r < 4; ++r)
                cwp += fmaxf(hd[r] + b1cL[T][r], 0.f) * w2cL[T][r];
        }
        cwp += __shfl_xor(cwp, 16);
        cwp += __shfl_xor(cwp, 32);
        float cw = cwp + b2c0;

        int jg = (bb << 9) + jrow + c;
        float rx = cix - coors[jg * 3 + 0];
        float ry = ciy - coors[jg * 3 + 1];
        float rz = ciz - coors[jg * 3 + 2];
        cax += cw * rx; cay += cw * ry; caz += cw * rz;
    }

    // m_i: reduce macc8 over the 16 c-lanes (butterfly)
    #pragma unroll
    for (int msk = 1; msk <= 8; msk <<= 1)
        #pragma unroll
        for (int p = 0; p < 8; ++p) macc8[p] += __shfl_xor(macc8[p], msk);
    if (c == 0 && g < 2) {
        #pragma unroll
        for (int p = 0; p < 8; ++p) sRedM[wv][g * 8 + p] = macc8[p];
    }
    // coors: full-wave reduce (each edge counted 4x -> scale 0.25 at the end)
    #pragma unroll
    for (int msk = 1; msk <= 32; msk <<= 1) {
        cax += __shfl_xor(cax, msk);
        cay += __shfl_xor(cay, msk);
        caz += __shfl_xor(caz, msk);
    }
    if (lane == 0) { sRedC[wv][0] = cax; sRedC[wv][1] = cay; sRedC[wv][2] = caz; }
    __syncthreads();

    if (t < 16) sFin[t] = sRedM[0][t] + sRedM[1][t] + sRedM[2][t] + sRedM[3][t];
    if (t >= 32 && t < 35) {
        int k = t - 32;
        out[OUT_H + bi * 3 + k] =
            (sRedC[0][k] + sRedC[1][k] + sRedC[2][k] + sRedC[3][k]) * 0.25f;
    }
    __syncthreads();

    // ================= node MLP =================
    if (t < 128) {
        float a = b1h[t];
        const float* fp = feats + bi * 64;
        #pragma unroll 8
        for (int k = 0; k < 64; ++k) a += fp[k] * w1h[k * 128 + t];
        #pragma unroll
        for (int k = 0; k < 16; ++k) a += sFin[k] * w1h[(64 + k) * 128 + t];
        sHid[t] = fmaxf(a, 0.f);
    }
    __syncthreads();
    if (t < 64) {
        float a = b2h[t];
        #pragma unroll 8
        for (int k = 0; k < 128; ++k) a += sHid[k] * w2h[k * 64 + t];
        out[bi * 64 + t] = a;
    }
}

extern "C" void kernel_launch(void* const* d_in, const int* in_sizes, int n_in,
                              void* d_out, int out_size, void* d_ws, size_t ws_size,
                              hipStream_t stream)
{
    const float* feats = (const float*)d_in[0];
    const float* coors = (const float*)d_in[1];
    const float* w1e   = (const float*)d_in[2];
    const float* b1e   = (const float*)d_in[3];
    const float* w2e   = (const float*)d_in[4];
    const float* b2e   = (const float*)d_in[5];
    const float* w1c   = (const float*)d_in[6];
    const float* b1c   = (const float*)d_in[7];
    const float* w2c   = (const float*)d_in[8];
    const float* b2c   = (const float*)d_in[9];
    const float* w1h   = (const float*)d_in[10];
    const float* b1h   = (const float*)d_in[11];
    const float* w2h   = (const float*)d_in[12];
    const float* b2h   = (const float*)d_in[13];
    float* out = (float*)d_out;

    char* ws = (char*)d_ws;
    f16*   Q1   = (f16*)ws;                                    // 589824 B
    float* P2F  = (float*)(ws + 589824);                       // 1179648 B (frag order, f32)
    f16*   Wd   = (f16*)(ws + 589824 + 1179648);               // 5184 B
    f16*   W2F  = (f16*)(ws + 589824 + 1179648 + 5184);        // 9216 B
    f16*   W1CB = (f16*)(ws + 589824 + 1179648 + 5184 + 9216); // 4096 B

    egnn_pre<<<2327, 256, 0, stream>>>(feats, w1e, b1e, w2e, w1c, Q1, P2F, Wd, W2F, W1CB);
    egnn_edge<<<1024, 256, 0, stream>>>(feats, coors, b2e, b1c, w2c, b2c,
                                        w1h, b1h, w2h, b2h,
                                        Q1, P2F, Wd, W2F, W1CB, out);
}